// Round 1
// baseline (672.794 us; speedup 1.0000x reference)
//
#include <hip/hip_runtime.h>
#include <hip/hip_bf16.h>
#include <math.h>

#define T_ 4096
#define H_ 1024
#define E_ 8
#define KTOP 2
#define I_ 2048
#define EPS_ 1e-5f
#define LDST 72   // LDS row stride in bf16 elems (144 B, 16B-aligned, bank-balanced)

using bf16x8 = __attribute__((ext_vector_type(8))) short;
using f32x4  = __attribute__((ext_vector_type(4))) float;

static __device__ __forceinline__ unsigned short f2bf(float f) {
    union { float f; unsigned int u; } v; v.f = f;
    unsigned int u = v.u;
    u += 0x7fffu + ((u >> 16) & 1u);   // RNE
    return (unsigned short)(u >> 16);
}

// ---------------- Kernel 1: RMSNorm + gate logits + top-2 routing ----------
__global__ __launch_bounds__(256) void k_norm_gate(
    const float* __restrict__ x, const float* __restrict__ scale,
    const float* __restrict__ gk, const float* __restrict__ gb,
    unsigned short* __restrict__ normed_bf,
    int* __restrict__ counts, int* __restrict__ tok_list, float* __restrict__ w_list)
{
    int t = blockIdx.x;
    int tid = threadIdx.x;
    int lane = tid & 63, wave = tid >> 6;

    float4 xv = ((const float4*)(x + (size_t)t * H_))[tid];
    float ss = xv.x*xv.x + xv.y*xv.y + xv.z*xv.z + xv.w*xv.w;
    #pragma unroll
    for (int off = 32; off; off >>= 1) ss += __shfl_down(ss, off);

    __shared__ float red[4];
    __shared__ float s_inv;
    if (lane == 0) red[wave] = ss;
    __syncthreads();
    if (tid == 0) {
        float tot = red[0] + red[1] + red[2] + red[3];
        s_inv = 1.0f / sqrtf(tot / (float)H_ + EPS_);
    }
    __syncthreads();
    float inv = s_inv;

    float4 sv = ((const float4*)scale)[tid];
    float nv[4];
    nv[0] = xv.x*inv*sv.x; nv[1] = xv.y*inv*sv.y;
    nv[2] = xv.z*inv*sv.z; nv[3] = xv.w*inv*sv.w;
    ushort4 nb;
    nb.x = f2bf(nv[0]); nb.y = f2bf(nv[1]); nb.z = f2bf(nv[2]); nb.w = f2bf(nv[3]);
    ((ushort4*)(normed_bf + (size_t)t * H_))[tid] = nb;

    // gate logits partials (fp32 normed, matching reference precision)
    float p[E_];
    #pragma unroll
    for (int e = 0; e < E_; e++) p[e] = 0.f;
    int h0 = tid * 4;
    #pragma unroll
    for (int j = 0; j < 4; j++) {
        const float4* g4 = (const float4*)(gk + (size_t)(h0 + j) * E_);
        float4 a = g4[0], b = g4[1];
        float n = nv[j];
        p[0] += n*a.x; p[1] += n*a.y; p[2] += n*a.z; p[3] += n*a.w;
        p[4] += n*b.x; p[5] += n*b.y; p[6] += n*b.z; p[7] += n*b.w;
    }
    __shared__ float pr[E_][4];
    #pragma unroll
    for (int e = 0; e < E_; e++) {
        float v = p[e];
        #pragma unroll
        for (int off = 32; off; off >>= 1) v += __shfl_down(v, off);
        if (lane == 0) pr[e][wave] = v;
    }
    __syncthreads();
    if (tid == 0) {
        float lg[E_];
        #pragma unroll
        for (int e = 0; e < E_; e++)
            lg[e] = pr[e][0] + pr[e][1] + pr[e][2] + pr[e][3] + gb[e];
        int b0 = -1, b1 = -1; float l0 = -1e30f, l1 = -1e30f;
        #pragma unroll
        for (int e = 0; e < E_; e++) {
            if (lg[e] > l0) { l1 = l0; b1 = b0; l0 = lg[e]; b0 = e; }
            else if (lg[e] > l1) { l1 = lg[e]; b1 = e; }
        }
        float e1 = expf(l1 - l0);
        float w0 = 1.f / (1.f + e1);
        float w1 = e1 / (1.f + e1);
        int p0 = atomicAdd(&counts[b0], 1);
        tok_list[b0 * T_ + p0] = t * 2 + 0; w_list[b0 * T_ + p0] = w0;
        int p1 = atomicAdd(&counts[b1], 1);
        tok_list[b1 * T_ + p1] = t * 2 + 1; w_list[b1 * T_ + p1] = w1;
    }
}

// ---------------- Kernel 2: out = x (residual init) ------------------------
__global__ __launch_bounds__(256) void k_init_out(
    const float* __restrict__ x, float* __restrict__ out)
{
    size_t i = (size_t)blockIdx.x * 256 + threadIdx.x;
    ((float4*)out)[i] = ((const float4*)x)[i];
}

// ---------------- Kernel 3: GEMM1 (normed x W1^T) + SwiGLU -> act ----------
// Per expert: C[Ne, I] pairs (gate f=i, linear f=I+i). Tile 64 slots x 64 i.
__global__ __launch_bounds__(256) void k_mlp1(
    const float* __restrict__ w1, const float* __restrict__ b1,
    const unsigned short* __restrict__ normed_bf,
    const int* __restrict__ counts, const int* __restrict__ tok_list,
    unsigned short* __restrict__ act)
{
    int e = blockIdx.z;
    int Ne = counts[e];
    int mt0 = blockIdx.y * 64;
    if (mt0 >= Ne) return;
    int it0 = blockIdx.x * 64;
    int tid = threadIdx.x;
    int lane = tid & 63, wave = tid >> 6;
    int quad = lane >> 4, m16 = lane & 15;

    __shared__ unsigned short lA[64 * LDST];
    __shared__ unsigned short lBg[64 * LDST];
    __shared__ unsigned short lBl[64 * LDST];
    __shared__ int ls_tk[64];

    if (tid < 64) {
        int slot = mt0 + tid;
        ls_tk[tid] = (slot < Ne) ? tok_list[e * T_ + slot] : -1;
    }
    __syncthreads();

    f32x4 accg[4], accl[4];
    #pragma unroll
    for (int ns = 0; ns < 4; ns++) {
        accg[ns] = (f32x4){0.f, 0.f, 0.f, 0.f};
        accl[ns] = (f32x4){0.f, 0.f, 0.f, 0.f};
    }

    const size_t w1base = (size_t)e * 2 * I_ * H_;
    int rA = tid >> 3, sgA = tid & 7;      // A: 8 threads/row, 16B each
    int nB = tid >> 2, sgB = tid & 3;      // B: 4 threads/row, 64B fp32 each

    for (int kk = 0; kk < H_; kk += 64) {
        #pragma unroll
        for (int rr = 0; rr < 64; rr += 32) {
            int r = rA + rr;
            int tk = ls_tk[r];
            uint4 v = make_uint4(0u, 0u, 0u, 0u);
            if (tk >= 0)
                v = *(const uint4*)(normed_bf + (size_t)(tk >> 1) * H_ + kk + sgA * 8);
            *(uint4*)(&lA[r * LDST + sgA * 8]) = v;
        }
        {
            const float* srcg = w1 + w1base + (size_t)(it0 + nB) * H_ + kk + sgB * 16;
            const float* srcl = srcg + (size_t)I_ * H_;
            unsigned short tg[16], tl[16];
            #pragma unroll
            for (int q = 0; q < 4; q++) {
                float4 fg = ((const float4*)srcg)[q];
                float4 fl = ((const float4*)srcl)[q];
                tg[q*4+0] = f2bf(fg.x); tg[q*4+1] = f2bf(fg.y);
                tg[q*4+2] = f2bf(fg.z); tg[q*4+3] = f2bf(fg.w);
                tl[q*4+0] = f2bf(fl.x); tl[q*4+1] = f2bf(fl.y);
                tl[q*4+2] = f2bf(fl.z); tl[q*4+3] = f2bf(fl.w);
            }
            *(uint4*)(&lBg[nB * LDST + sgB * 16])     = *(uint4*)(&tg[0]);
            *(uint4*)(&lBg[nB * LDST + sgB * 16 + 8]) = *(uint4*)(&tg[8]);
            *(uint4*)(&lBl[nB * LDST + sgB * 16])     = *(uint4*)(&tl[0]);
            *(uint4*)(&lBl[nB * LDST + sgB * 16 + 8]) = *(uint4*)(&tl[8]);
        }
        __syncthreads();
        #pragma unroll
        for (int ks = 0; ks < 64; ks += 32) {
            bf16x8 af = *(const bf16x8*)(&lA[(wave * 16 + m16) * LDST + ks + quad * 8]);
            #pragma unroll
            for (int ns = 0; ns < 4; ns++) {
                bf16x8 bg = *(const bf16x8*)(&lBg[(ns * 16 + m16) * LDST + ks + quad * 8]);
                accg[ns] = __builtin_amdgcn_mfma_f32_16x16x32_bf16(af, bg, accg[ns], 0, 0, 0);
                bf16x8 bl = *(const bf16x8*)(&lBl[(ns * 16 + m16) * LDST + ks + quad * 8]);
                accl[ns] = __builtin_amdgcn_mfma_f32_16x16x32_bf16(af, bl, accl[ns], 0, 0, 0);
            }
        }
        __syncthreads();
    }

    // epilogue: bias + SwiGLU, write bf16 act
    #pragma unroll
    for (int reg = 0; reg < 4; reg++) {
        int row = wave * 16 + quad * 4 + reg;
        int tk = ls_tk[row];
        if (tk < 0) continue;
        #pragma unroll
        for (int ns = 0; ns < 4; ns++) {
            int i = it0 + ns * 16 + m16;
            float g = accg[ns][reg] + b1[(size_t)e * 2 * I_ + i];
            float l = accl[ns][reg] + b1[(size_t)e * 2 * I_ + I_ + i];
            g = fminf(g, 7.f);
            l = fminf(fmaxf(l, -7.f), 7.f);
            float sw = g / (1.f + expf(-1.702f * g));
            float a = sw * (l + 1.f);
            act[(size_t)tk * I_ + i] = f2bf(a);
        }
    }
}

// ---------------- Kernel 4: GEMM2 (act x W2^T), weighted scatter-add -------
__global__ __launch_bounds__(256) void k_mlp2(
    const float* __restrict__ w2, const float* __restrict__ b2,
    const unsigned short* __restrict__ act,
    const int* __restrict__ counts, const int* __restrict__ tok_list,
    const float* __restrict__ w_list,
    float* __restrict__ out)
{
    int e = blockIdx.z;
    int Ne = counts[e];
    int mt0 = blockIdx.y * 64;
    if (mt0 >= Ne) return;
    int ht0 = blockIdx.x * 64;
    int tid = threadIdx.x;
    int lane = tid & 63, wave = tid >> 6;
    int quad = lane >> 4, m16 = lane & 15;

    __shared__ unsigned short lA[64 * LDST];
    __shared__ unsigned short lB[64 * LDST];
    __shared__ int ls_tk[64];
    __shared__ float ls_w[64];

    if (tid < 64) {
        int slot = mt0 + tid;
        ls_tk[tid] = (slot < Ne) ? tok_list[e * T_ + slot] : -1;
        ls_w[tid]  = (slot < Ne) ? w_list[e * T_ + slot] : 0.f;
    }
    __syncthreads();

    f32x4 acc[4];
    #pragma unroll
    for (int ns = 0; ns < 4; ns++) acc[ns] = (f32x4){0.f, 0.f, 0.f, 0.f};

    const size_t w2base = (size_t)e * H_ * I_;
    int rA = tid >> 3, sgA = tid & 7;
    int nB = tid >> 2, sgB = tid & 3;

    for (int kk = 0; kk < I_; kk += 64) {
        #pragma unroll
        for (int rr = 0; rr < 64; rr += 32) {
            int r = rA + rr;
            int tk = ls_tk[r];
            uint4 v = make_uint4(0u, 0u, 0u, 0u);
            if (tk >= 0)
                v = *(const uint4*)(act + (size_t)tk * I_ + kk + sgA * 8);
            *(uint4*)(&lA[r * LDST + sgA * 8]) = v;
        }
        {
            const float* src = w2 + w2base + (size_t)(ht0 + nB) * I_ + kk + sgB * 16;
            unsigned short tb[16];
            #pragma unroll
            for (int q = 0; q < 4; q++) {
                float4 f4 = ((const float4*)src)[q];
                tb[q*4+0] = f2bf(f4.x); tb[q*4+1] = f2bf(f4.y);
                tb[q*4+2] = f2bf(f4.z); tb[q*4+3] = f2bf(f4.w);
            }
            *(uint4*)(&lB[nB * LDST + sgB * 16])     = *(uint4*)(&tb[0]);
            *(uint4*)(&lB[nB * LDST + sgB * 16 + 8]) = *(uint4*)(&tb[8]);
        }
        __syncthreads();
        #pragma unroll
        for (int ks = 0; ks < 64; ks += 32) {
            bf16x8 af = *(const bf16x8*)(&lA[(wave * 16 + m16) * LDST + ks + quad * 8]);
            #pragma unroll
            for (int ns = 0; ns < 4; ns++) {
                bf16x8 bf = *(const bf16x8*)(&lB[(ns * 16 + m16) * LDST + ks + quad * 8]);
                acc[ns] = __builtin_amdgcn_mfma_f32_16x16x32_bf16(af, bf, acc[ns], 0, 0, 0);
            }
        }
        __syncthreads();
    }

    #pragma unroll
    for (int reg = 0; reg < 4; reg++) {
        int row = wave * 16 + quad * 4 + reg;
        int tk = ls_tk[row];
        if (tk < 0) continue;
        int t = tk >> 1;
        float wgt = ls_w[row];
        #pragma unroll
        for (int ns = 0; ns < 4; ns++) {
            int h = ht0 + ns * 16 + m16;
            float v = acc[ns][reg] + b2[(size_t)e * H_ + h];
            atomicAdd(&out[(size_t)t * H_ + h], wgt * v);
        }
    }
}

// ---------------- launcher -------------------------------------------------
extern "C" void kernel_launch(void* const* d_in, const int* in_sizes, int n_in,
                              void* d_out, int out_size, void* d_ws, size_t ws_size,
                              hipStream_t stream) {
    const float* x     = (const float*)d_in[0];
    const float* scale = (const float*)d_in[1];
    const float* gk    = (const float*)d_in[2];
    const float* gb    = (const float*)d_in[3];
    const float* w1    = (const float*)d_in[4];
    const float* b1    = (const float*)d_in[5];
    const float* w2    = (const float*)d_in[6];
    const float* b2    = (const float*)d_in[7];
    float* out = (float*)d_out;

    char* ws = (char*)d_ws;
    unsigned short* normed_bf = (unsigned short*)ws;                       // 8 MB
    unsigned short* act       = (unsigned short*)(ws + (size_t)8*1024*1024);   // 32 MB
    char* ctl                 = ws + (size_t)40*1024*1024;
    int*   counts   = (int*)ctl;                                           // 32 B (pad 256)
    int*   tok_list = (int*)(ctl + 256);                                   // E*T*4
    float* w_list   = (float*)(ctl + 256 + (size_t)E_*T_*4);               // E*T*4

    hipMemsetAsync(counts, 0, E_ * sizeof(int), stream);

    k_norm_gate<<<dim3(T_), dim3(256), 0, stream>>>(x, scale, gk, gb,
                                                    normed_bf, counts, tok_list, w_list);
    k_init_out<<<dim3(T_ * H_ / (256 * 4)), dim3(256), 0, stream>>>(x, out);
    k_mlp1<<<dim3(I_ / 64, T_ / 64, E_), dim3(256), 0, stream>>>(w1, b1, normed_bf,
                                                                 counts, tok_list, act);
    k_mlp2<<<dim3(H_ / 64, T_ / 64, E_), dim3(256), 0, stream>>>(w2, b2, act,
                                                                 counts, tok_list, w_list, out);
}